// Round 12
// baseline (459.498 us; speedup 1.0000x reference)
//
#include <hip/hip_runtime.h>
#include <hip/hip_bf16.h>
#include <stdint.h>

typedef __attribute__((ext_vector_type(4))) float f32x4;
typedef __attribute__((ext_vector_type(8))) short short8;

#define DIM_S 4096
#define DIM_IN 1536
#define DIM_OUT 3072
#define NB 8
#define NORG 4

#define XB_ELEMS (NB * DIM_S * DIM_IN)      /* 50331648 */
#define WT_ELEMS (NORG * DIM_OUT * DIM_IN)  /* 18874368 */
#define WS_NEED ((size_t)(XB_ELEMS + WT_ELEMS) * 2)

__device__ __forceinline__ unsigned short f2bf(float f) {
    union { __hip_bfloat16 h; unsigned short u; } c;
    c.h = __float2bfloat16(f);
    return c.u;
}

__device__ __forceinline__ void gload16(const void* g, void* l) {
    __builtin_amdgcn_global_load_lds(
        (const __attribute__((address_space(1))) unsigned int*)g,
        (__attribute__((address_space(3))) unsigned int*)l, 16, 0, 0);
}

// ---------- pass 1a: x f32 -> bf16 ----------
__global__ __launch_bounds__(256) void cvt_x(const float* __restrict__ x,
                                             unsigned short* __restrict__ xb) {
    const int nchunk = XB_ELEMS / 8;
    for (int c = blockIdx.x * 256 + threadIdx.x; c < nchunk; c += gridDim.x * 256) {
        const float4 v0 = *reinterpret_cast<const float4*>(x + (size_t)c * 8);
        const float4 v1 = *reinterpret_cast<const float4*>(x + (size_t)c * 8 + 4);
        union { unsigned short u[8]; short8 v; } p;
        p.u[0] = f2bf(v0.x); p.u[1] = f2bf(v0.y); p.u[2] = f2bf(v0.z); p.u[3] = f2bf(v0.w);
        p.u[4] = f2bf(v1.x); p.u[5] = f2bf(v1.y); p.u[6] = f2bf(v1.z); p.u[7] = f2bf(v1.w);
        *reinterpret_cast<short8*>(xb + (size_t)c * 8) = p.v;
    }
}

// ---------- pass 1b: W [org][K][N] f32 -> W^T [org][N][K] bf16 ----------
__global__ __launch_bounds__(256) void cvt_wt(const float* __restrict__ w,
                                              unsigned short* __restrict__ wt) {
    __shared__ unsigned short T[64][68];
    const int bid = blockIdx.x;
    const int org = bid / (24 * 48);
    const int rem = bid % (24 * 48);
    const int k0 = (rem / 48) * 64;
    const int n0 = (rem % 48) * 64;
    const float* __restrict__ wp = w + (size_t)org * DIM_IN * DIM_OUT;
    unsigned short* __restrict__ op = wt + (size_t)org * DIM_OUT * DIM_IN;
    const int t = threadIdx.x;
    #pragma unroll
    for (int i = 0; i < 4; ++i) {
        const int c = t + 256 * i;
        const int kk = c >> 4, nq = (c & 15) * 4;
        const float4 v = *reinterpret_cast<const float4*>(
            wp + (size_t)(k0 + kk) * DIM_OUT + n0 + nq);
        ushort4 pv;
        pv.x = f2bf(v.x); pv.y = f2bf(v.y); pv.z = f2bf(v.z); pv.w = f2bf(v.w);
        *reinterpret_cast<ushort4*>(&T[kk][nq]) = pv;
    }
    __syncthreads();
    #pragma unroll
    for (int i = 0; i < 2; ++i) {
        const int c = t + 256 * i;
        const int n = c >> 3, k8 = (c & 7) * 8;
        union { unsigned short u[8]; short8 v; } p;
        #pragma unroll
        for (int j = 0; j < 8; ++j) p.u[j] = T[k8 + j][n];
        *reinterpret_cast<short8*>(op + (size_t)(n0 + n) * DIM_IN + k0 + k8) = p.v;
    }
}

// ---------- pass 2: 256x256 8-phase GEMM, deep counted pipeline ----------
// Identical to R11 EXCEPT the block remap, which now correctly keeps the
// XCD base: xcd = bid&7 owns batch xcd; lid = bid>>3 in [0,192) gives the
// 2x2 L2 super-tile order (col pair fastest, then 16 rows, then 6 supercols).
// Pipeline: A+B staged PAIRED (4 gloads) at P1/P3/P5/P7; vmcnt(8) at odd-
// phase ends only -> stage confirmed 4 phases after issue, 8-12 in flight.
// Hazard ledger (per-wave, verified): prologue leaves 8 outstanding; each
// odd phase +4 then WAIT8 confirms exactly the slot first read two phases
// later, one barrier ahead; WAR covered by WAITL-before-MM + barrier.
__global__ __launch_bounds__(512, 2) void mol_gemm_8p(
    const unsigned short* __restrict__ xb, const int* __restrict__ orgidx,
    const unsigned short* __restrict__ wt, const float* __restrict__ bias,
    float* __restrict__ out)
{
    __shared__ __align__(16) unsigned short LDS[2][4][8192];  // 128 KiB

    const int tid  = threadIdx.x;
    const int lane = tid & 63;
    const int wave = tid >> 6;
    const int wr = wave >> 2;      // 0..1  (M half)
    const int wc = wave & 3;       // 0..3  (N quarter)
    const int l15 = lane & 15;
    const int q16 = lane >> 4;

    // XCD remap + 2x2 L2 super-tile (FIXED): each XCD = one batch.
    const int bid = blockIdx.x;
    const int xcd = bid & 7;
    const int lid = bid >> 3;                 // 0..191 within XCD
    const int sc  = lid >> 5;                 // 0..5  super-col (pair of cols)
    const int r16 = (lid >> 1) & 15;          // 0..15 row-block within batch
    const int c2  = lid & 1;                  // col within pair
    const int row0 = (xcd * 16 + r16) * 256;
    const int col0 = (sc * 2 + c2) * 256;
    const int org  = orgidx[xcd];

    const unsigned short* __restrict__ Abase = xb + (size_t)row0 * DIM_IN;
    const unsigned short* __restrict__ Bbase =
        wt + (size_t)org * DIM_OUT * DIM_IN + (size_t)col0 * DIM_IN;

    // staging source (pre-swizzled global k-quad, st_16x32)
    const int rA = tid >> 2;
    const int qs = ((tid & 3) ^ (((tid >> 5) & 1) << 1)) * 8;
    const unsigned short* pA0 = Abase + (size_t)rA * DIM_IN + qs;
    const unsigned short* pA1 = Abase + (size_t)(128 + rA) * DIM_IN + qs;
    const unsigned short* pB0 = Bbase + (size_t)rA * DIM_IN + qs;
    const unsigned short* pB1 = Bbase + (size_t)(128 + rA) * DIM_IN + qs;

    const int d0 = wave * 512;
    const int d1 = 4096 + wave * 512;

    // ds_read byte offsets (swizzled) -> 32-bit LDS addresses for asm
    const int swb = ((l15 >> 3) & 1) << 1;
    const int offA0 = ((wr * 128 + l15) * 32 + ((q16 ^ swb) << 3)) * 2;
    const int offB0 = ((wc * 64  + l15) * 32 + ((q16 ^ swb) << 3)) * 2;
    const unsigned ldsbase = (unsigned)(unsigned long long)
        (const __attribute__((address_space(3))) unsigned short*)&LDS[0][0][0];
    const unsigned adrA = ldsbase + (unsigned)offA0;
    const unsigned adrB = ldsbase + (unsigned)offB0;

    f32x4 acc[8][4] = {};
    short8 af[2][4], bfr[2][4];

// stage A-slot kk AND B-slot kk of buf at global k offset (4 gloads)
#define STG2(buf, kk, kofs) do {                               \
        gload16(pA0 + (kofs), &LDS[buf][kk][d0]);              \
        gload16(pA1 + (kofs), &LDS[buf][kk][d1]);              \
        gload16(pB0 + (kofs), &LDS[buf][2 + (kk)][d0]);        \
        gload16(pB1 + (kofs), &LDS[buf][2 + (kk)][d1]);        \
    } while (0)

#define DSR(dst, addr, imm)                                                 \
    asm volatile("ds_read_b128 %0, %1 offset:%c2"                           \
                 : "=v"(dst) : "v"(addr), "i"(imm))

#define RD_A4(dst, buf, kk, mih) do {                                       \
        const unsigned aA_ = adrA +                                         \
            ((buf) * 65536u + (kk) * 16384u + (mih) * 4096u);               \
        DSR(af[dst][0], aA_, 0);    DSR(af[dst][1], aA_, 1024);             \
        DSR(af[dst][2], aA_, 2048); DSR(af[dst][3], aA_, 3072);             \
    } while (0)

#define RD_B4(dst, buf, kk) do {                                            \
        const unsigned aB_ = adrB +                                         \
            ((buf) * 65536u + (2 + (kk)) * 16384u);                         \
        DSR(bfr[dst][0], aB_, 0);    DSR(bfr[dst][1], aB_, 1024);           \
        DSR(bfr[dst][2], aB_, 2048); DSR(bfr[dst][3], aB_, 3072);           \
    } while (0)

#define MM(ca, cb, mih) do {                                                \
        __builtin_amdgcn_s_setprio(1);                                      \
        _Pragma("unroll")                                                   \
        for (int i_ = 0; i_ < 4; ++i_) {                                    \
            _Pragma("unroll")                                               \
            for (int n_ = 0; n_ < 4; ++n_)                                  \
                acc[(mih)*4 + i_][n_] =                                     \
                    __builtin_amdgcn_mfma_f32_16x16x32_bf16(                \
                        af[ca][i_], bfr[cb][n_],                            \
                        acc[(mih)*4 + i_][n_], 0, 0, 0);                    \
        }                                                                   \
        __builtin_amdgcn_s_setprio(0);                                      \
    } while (0)

#define BAR  do { __builtin_amdgcn_s_barrier();                             \
                  asm volatile("" ::: "memory"); } while (0)
#define WAIT8 asm volatile("s_waitcnt vmcnt(8)" ::: "memory")
#define WAITL(n) do { asm volatile("s_waitcnt lgkmcnt(" #n ")");            \
                      __builtin_amdgcn_sched_barrier(0); } while (0)
#define KADV(k) do { if ((k) < 1504) (k) += 32; } while (0)

    // ---- prologue: buf0 k0+k1 (tile0), buf1 k0 (tile1); 12 loads ----
    STG2(0, 0, 0);     // tile0 k0 (A+B)
    STG2(0, 1, 32);    // tile0 k1
    STG2(1, 0, 64);    // tile1 k0
    WAIT8;             // tile0-k0 A+B landed (oldest 4)
    BAR;
    RD_A4(0, 0, 0, 0); // af0 <- A(t0,k0,mih0)
    RD_B4(0, 0, 0);    // bf0 <- B(t0,k0)

    int kS = 96;

    // Stages: P1 -> buf1-k1 (t+1), P3 -> buf0-k0 (t+2), P5 -> buf0-k1 (t+2),
    // P7 -> buf1-k0 (t+3); 4 gloads each; single kS counter (+32/stage).
#define TILE2() do {                                                          \
  /*P1*/ STG2(1,1,kS); KADV(kS); RD_A4(1, 0,0,1);                             \
         WAITL(4); MM(0,0,0); WAIT8; BAR;                                     \
  /*P2*/ RD_A4(0, 0,1,0); RD_B4(1, 0,1);                                      \
         WAITL(8); MM(1,0,1); BAR;                                            \
  /*P3*/ STG2(0,0,kS); KADV(kS); RD_A4(1, 0,1,1);                             \
         WAITL(4); MM(0,1,0); WAIT8; BAR;                                     \
  /*P4*/ RD_A4(0, 1,0,0); RD_B4(0, 1,0);                                      \
         WAITL(8); MM(1,1,1); BAR;                                            \
  /*P5*/ STG2(0,1,kS); KADV(kS); RD_A4(1, 1,0,1);                             \
         WAITL(4); MM(0,0,0); WAIT8; BAR;                                     \
  /*P6*/ RD_A4(0, 1,1,0); RD_B4(1, 1,1);                                      \
         WAITL(8); MM(1,0,1); BAR;                                            \
  /*P7*/ STG2(1,0,kS); KADV(kS); RD_A4(1, 1,1,1);                             \
         WAITL(4); MM(0,1,0); WAIT8; BAR;                                     \
  /*P8*/ RD_A4(0, 0,0,0); RD_B4(0, 0,0);                                      \
         WAITL(8); MM(1,1,1); BAR;                                            \
} while (0)

    #pragma unroll 1
    for (int i = 0; i < 12; ++i) {   // 24 K-tiles(64), 2 per TILE2
        TILE2();
    }

    asm volatile("s_waitcnt lgkmcnt(0)");

    // ---- epilogue: bias + store f32 ----
    const float* __restrict__ bptr = bias + (size_t)org * DIM_OUT;
    const int crow = q16 * 4;
    const int ccol = l15;
    #pragma unroll
    for (int ni = 0; ni < 4; ++ni) {
        const int gc = col0 + wc * 64 + ni * 16 + ccol;
        const float bv = bptr[gc];
        #pragma unroll
        for (int mi = 0; mi < 8; ++mi) {
            const int gr = row0 + wr * 128 + mi * 16 + crow;
            #pragma unroll
            for (int r = 0; r < 4; ++r)
                out[(size_t)(gr + r) * DIM_OUT + gc] = acc[mi][ni][r] + bv;
        }
    }
#undef STG2
#undef DSR
#undef RD_A4
#undef RD_B4
#undef MM
#undef BAR
#undef WAIT8
#undef WAITL
#undef KADV
#undef TILE2
}

// ---------- fallback (R2 kernel) if ws too small ----------
#define BM 128
#define BN 128
#define BK 32
#define LDK 40
union BF8 { unsigned short u[8]; short8 v; };

__global__ __launch_bounds__(256) void mol_gemm_fb(
    const float* __restrict__ x, const int* __restrict__ orgidx,
    const float* __restrict__ weight, const float* __restrict__ bias,
    float* __restrict__ out)
{
    __shared__ __align__(16) unsigned short Alds[2][BM][LDK];
    __shared__ __align__(16) unsigned short Blds[2][BN][LDK];

    const int tid  = threadIdx.x;
    const int lane = tid & 63;
    const int wave = tid >> 6;
    const int wr = wave >> 1, wc = wave & 1;

    const int bid = blockIdx.x;
    const int id  = (bid & 7) * 768 + (bid >> 3);
    const int row0 = (id / 24) * BM;
    const int col0 = (id % 24) * BN;

    const int batch = row0 / DIM_S;
    const int org   = orgidx[batch];
    const float* __restrict__ W = weight + (size_t)org * DIM_IN * DIM_OUT;

    f32x4 acc[4][4] = {};
    const int ar  = tid >> 2;
    const int ak8 = (tid & 3) * 8;
    const int bn  = tid & 127;
    const int bg0 = tid >> 7;
    const float* __restrict__ xbase = x + (size_t)row0 * DIM_IN;
    const float* __restrict__ wbase = W + col0 + bn;

    auto stage = [&](int buf, int k0) {
        #pragma unroll
        for (int i = 0; i < 2; ++i) {
            const int r = ar + 64 * i;
            const float* xp = xbase + (size_t)r * DIM_IN + k0 + ak8;
            const float4 v0 = *reinterpret_cast<const float4*>(xp);
            const float4 v1 = *reinterpret_cast<const float4*>(xp + 4);
            BF8 p;
            p.u[0] = f2bf(v0.x); p.u[1] = f2bf(v0.y);
            p.u[2] = f2bf(v0.z); p.u[3] = f2bf(v0.w);
            p.u[4] = f2bf(v1.x); p.u[5] = f2bf(v1.y);
            p.u[6] = f2bf(v1.z); p.u[7] = f2bf(v1.w);
            *reinterpret_cast<short8*>(&Alds[buf][r][ak8]) = p.v;
        }
        #pragma unroll
        for (int j = 0; j < 2; ++j) {
            const int g = bg0 + 2 * j;
            const float* wp = wbase + (size_t)(k0 + 8 * g) * DIM_OUT;
            BF8 p;
            #pragma unroll
            for (int r = 0; r < 8; ++r) p.u[r] = f2bf(wp[(size_t)r * DIM_OUT]);
            *reinterpret_cast<short8*>(&Blds[buf][bn][8 * g]) = p.v;
        }
    };

    stage(0, 0);
    const int nk = DIM_IN / BK;
    const int kq = (lane >> 4) * 8;
    const int lr = lane & 15;

    for (int t = 0; t < nk; ++t) {
        __syncthreads();
        const int cur = t & 1;
        if (t + 1 < nk) stage(cur ^ 1, (t + 1) * BK);
        short8 a[4], b[4];
        #pragma unroll
        for (int mi = 0; mi < 4; ++mi)
            a[mi] = *reinterpret_cast<const short8*>(&Alds[cur][wr * 64 + mi * 16 + lr][kq]);
        #pragma unroll
        for (int ni = 0; ni < 4; ++ni)
            b[ni] = *reinterpret_cast<const short8*>(&Blds[cur][wc * 64 + ni * 16 + lr][kq]);
        #pragma unroll
        for (int mi = 0; mi < 4; ++mi)
            #pragma unroll
            for (int ni = 0; ni < 4; ++ni)
                acc[mi][ni] = __builtin_amdgcn_mfma_f32_16x16x32_bf16(
                    a[mi], b[ni], acc[mi][ni], 0, 0, 0);
    }

    const float* __restrict__ bptr = bias + (size_t)org * DIM_OUT;
    const int crow = (lane >> 4) * 4;
    const int ccol = lane & 15;
    #pragma unroll
    for (int ni = 0; ni < 4; ++ni) {
        const int gc = col0 + wc * 64 + ni * 16 + ccol;
        const float bv = bptr[gc];
        #pragma unroll
        for (int mi = 0; mi < 4; ++mi) {
            const int gr = row0 + wr * 64 + mi * 16 + crow;
            #pragma unroll
            for (int r = 0; r < 4; ++r)
                out[(size_t)(gr + r) * DIM_OUT + gc] = acc[mi][ni][r] + bv;
        }
    }
}

extern "C" void kernel_launch(void* const* d_in, const int* in_sizes, int n_in,
                              void* d_out, int out_size, void* d_ws, size_t ws_size,
                              hipStream_t stream)
{
    const float* x      = (const float*)d_in[0];
    const int*   orgidx = (const int*)d_in[1];
    const float* weight = (const float*)d_in[2];
    const float* bias   = (const float*)d_in[3];
    float* out = (float*)d_out;

    if (ws_size >= WS_NEED) {
        unsigned short* xbp = (unsigned short*)d_ws;
        unsigned short* wtp = xbp + XB_ELEMS;
        cvt_x<<<dim3(2048), dim3(256), 0, stream>>>(x, xbp);
        cvt_wt<<<dim3(NORG * 24 * 48), dim3(256), 0, stream>>>(weight, wtp);
        mol_gemm_8p<<<dim3(1536), dim3(512), 0, stream>>>(xbp, orgidx, wtp, bias, out);
    } else {
        mol_gemm_fb<<<dim3(6144), dim3(256), 0, stream>>>(x, orgidx, weight, bias, out);
    }
}

// Round 14
// 402.012 us; speedup vs baseline: 1.1430x; 1.1430x over previous
//
#include <hip/hip_runtime.h>
#include <hip/hip_bf16.h>
#include <stdint.h>

typedef __attribute__((ext_vector_type(4)))  float f32x4;
typedef __attribute__((ext_vector_type(16))) float f32x16;
typedef __attribute__((ext_vector_type(8)))  short short8;

#define DIM_S 4096
#define DIM_IN 1536
#define DIM_OUT 3072
#define NB 8
#define NORG 4

#define XB_ELEMS (NB * DIM_S * DIM_IN)      /* 50331648 */
#define WT_ELEMS (NORG * DIM_OUT * DIM_IN)  /* 18874368 */
#define WS_NEED ((size_t)(XB_ELEMS + WT_ELEMS) * 2)
#define NWT_BLOCKS (NORG * 24 * 48)         /* 4608 */
#define NX_BLOCKS 2048

__device__ __forceinline__ unsigned short f2bf(float f) {
    union { __hip_bfloat16 h; unsigned short u; } c;
    c.h = __float2bfloat16(f);
    return c.u;
}

__device__ __forceinline__ void gload16(const void* g, void* l) {
    __builtin_amdgcn_global_load_lds(
        (const __attribute__((address_space(1))) unsigned int*)g,
        (__attribute__((address_space(3))) unsigned int*)l, 16, 0, 0);
}

// ---------- pass 1 (fused): W^T transpose-convert + x convert ----------
__global__ __launch_bounds__(256) void cvt_all(const float* __restrict__ x,
                                               const float* __restrict__ w,
                                               unsigned short* __restrict__ xb,
                                               unsigned short* __restrict__ wt) {
    const int t = threadIdx.x;
    if (blockIdx.x < NWT_BLOCKS) {
        __shared__ unsigned short T[64][68];
        const int bid = blockIdx.x;
        const int org = bid / (24 * 48);
        const int rem = bid % (24 * 48);
        const int k0 = (rem / 48) * 64;
        const int n0 = (rem % 48) * 64;
        const float* __restrict__ wp = w + (size_t)org * DIM_IN * DIM_OUT;
        unsigned short* __restrict__ op = wt + (size_t)org * DIM_OUT * DIM_IN;
        #pragma unroll
        for (int i = 0; i < 4; ++i) {
            const int c = t + 256 * i;
            const int kk = c >> 4, nq = (c & 15) * 4;
            const float4 v = *reinterpret_cast<const float4*>(
                wp + (size_t)(k0 + kk) * DIM_OUT + n0 + nq);
            ushort4 pv;
            pv.x = f2bf(v.x); pv.y = f2bf(v.y); pv.z = f2bf(v.z); pv.w = f2bf(v.w);
            *reinterpret_cast<ushort4*>(&T[kk][nq]) = pv;
        }
        __syncthreads();
        #pragma unroll
        for (int i = 0; i < 2; ++i) {
            const int c = t + 256 * i;
            const int n = c >> 3, k8 = (c & 7) * 8;
            union { unsigned short u[8]; short8 v; } p;
            #pragma unroll
            for (int j = 0; j < 8; ++j) p.u[j] = T[k8 + j][n];
            *reinterpret_cast<short8*>(op + (size_t)(n0 + n) * DIM_IN + k0 + k8) = p.v;
        }
    } else {
        const int nchunk = XB_ELEMS / 8;
        const int xb0 = blockIdx.x - NWT_BLOCKS;
        for (int c = xb0 * 256 + t; c < nchunk; c += NX_BLOCKS * 256) {
            const float4 v0 = *reinterpret_cast<const float4*>(x + (size_t)c * 8);
            const float4 v1 = *reinterpret_cast<const float4*>(x + (size_t)c * 8 + 4);
            union { unsigned short u[8]; short8 v; } p;
            p.u[0] = f2bf(v0.x); p.u[1] = f2bf(v0.y); p.u[2] = f2bf(v0.z); p.u[3] = f2bf(v0.w);
            p.u[4] = f2bf(v1.x); p.u[5] = f2bf(v1.y); p.u[6] = f2bf(v1.z); p.u[7] = f2bf(v1.w);
            *reinterpret_cast<short8*>(xb + (size_t)c * 8) = p.v;
        }
    }
}

// ---------- pass 2: 256x256 8-phase GEMM, 32x32x16 MFMA ----------
// R9 skeleton (verified ledger, passed) with fragment geometry swapped to
// v_mfma_f32_32x32x16_bf16: +15% matrix-pipe ceiling, 2x fewer MFMA instrs.
// LDS slots [256 rows][32 k] bf16, st_16x32 swizzle (conflicts=0). A-frag
// (mf,ks): lane l reads row wr*128+mf*32+(l&31), k = ks*16+(l>>5)*8; the
// swizzle XOR flips the ks bit per lane -> two per-lane bases adr*_ks{0,1}.
// WAITL counts (4 reads per RD macro) and vmcnt schedule identical to R9.
__global__ __launch_bounds__(512, 2) void mol_gemm_8p(
    const unsigned short* __restrict__ xb, const int* __restrict__ orgidx,
    const unsigned short* __restrict__ wt, const float* __restrict__ bias,
    float* __restrict__ out)
{
    __shared__ __align__(16) unsigned short LDS[2][4][8192];  // 128 KiB

    const int tid  = threadIdx.x;
    const int lane = tid & 63;
    const int wave = tid >> 6;
    const int wr = wave >> 2;      // 0..1  (M half, 128 rows)
    const int wc = wave & 3;       // 0..3  (N quarter, 64 cols)
    const int l31 = lane & 31;
    const int lhi = lane >> 5;     // 0..1

    // XCD-aware remap (R9): 1536 blocks = 8 XCDs x 192; col-fastest.
    const int bid = blockIdx.x;
    const int id  = (bid & 7) * 192 + (bid >> 3);
    const int row0 = (id / 12) * 256;
    const int col0 = (id % 12) * 256;
    const int org  = orgidx[row0 >> 12];

    const unsigned short* __restrict__ Abase = xb + (size_t)row0 * DIM_IN;
    const unsigned short* __restrict__ Bbase =
        wt + (size_t)org * DIM_OUT * DIM_IN + (size_t)col0 * DIM_IN;

    // staging source (pre-swizzled global k-quad, st_16x32) — unchanged
    const int rA = tid >> 2;
    const int qs = ((tid & 3) ^ (((tid >> 5) & 1) << 1)) * 8;
    const unsigned short* pA0 = Abase + (size_t)rA * DIM_IN + qs;
    const unsigned short* pA1 = Abase + (size_t)(128 + rA) * DIM_IN + qs;
    const unsigned short* pB0 = Bbase + (size_t)rA * DIM_IN + qs;
    const unsigned short* pB1 = Bbase + (size_t)(128 + rA) * DIM_IN + qs;

    const int d0 = wave * 512;
    const int d1 = 4096 + wave * 512;

    // ds_read per-lane bases: row r (bit3 = l31 bit3), chunk = (ks*2+lhi)^swb
    const int sflip = (l31 >> 3) & 1;                  // swizzle flips ks bit
    const unsigned ldsbase = (unsigned)(unsigned long long)
        (const __attribute__((address_space(3))) unsigned short*)&LDS[0][0][0];
    const unsigned rbA = ldsbase + (unsigned)((wr * 128 + l31) * 64 + lhi * 16);
    const unsigned rbB = ldsbase + (unsigned)((wc * 64  + l31) * 64 + lhi * 16);
    const unsigned adrA_ks0 = rbA + (unsigned)(sflip * 32);
    const unsigned adrA_ks1 = rbA + (unsigned)(32 - sflip * 32);
    const unsigned adrB_ks0 = rbB + (unsigned)(sflip * 32);
    const unsigned adrB_ks1 = rbB + (unsigned)(32 - sflip * 32);

    f32x16 acc[4][2] = {};          // [mf][nf], 128 AGPRs
    short8 af[2][4], bfr[2][4];     // [set][ml*2+ks] / [set][nf*2+ks]

#define STG(buf, slot, p0, p1, kofs) do {                      \
        gload16((p0) + (kofs), &LDS[buf][slot][d0]);           \
        gload16((p1) + (kofs), &LDS[buf][slot][d1]);           \
    } while (0)

#define DSR(dst, addr, imm)                                                 \
    asm volatile("ds_read_b128 %0, %1 offset:%c2"                           \
                 : "=v"(dst) : "v"(addr), "i"(imm))

// A frags for half mih: mf = mih*2 + ml, both ks.  4 reads.
#define RD_A4(dst, buf, kk, mih) do {                                       \
        const unsigned o_ = (buf) * 65536u + (kk) * 16384u;                 \
        DSR(af[dst][0], adrA_ks0, ((mih)*2 + 0) * 2048);                    \
        asm volatile("ds_read_b128 %0, %1 offset:%c2"                       \
            : "=v"(af[dst][1]) : "v"(adrA_ks1 + o_), "i"(((mih)*2+0)*2048));\
        asm volatile("ds_read_b128 %0, %1 offset:%c2"                       \
            : "=v"(af[dst][2]) : "v"(adrA_ks0 + o_), "i"(((mih)*2+1)*2048));\
        asm volatile("ds_read_b128 %0, %1 offset:%c2"                       \
            : "=v"(af[dst][3]) : "v"(adrA_ks1 + o_), "i"(((mih)*2+1)*2048));\
    } while (0)

// NOTE: first DSR above needs the o_ too — use uniform form instead:
#undef RD_A4
#define RD_A4(dst, buf, kk, mih) do {                                       \
        const unsigned o0_ = adrA_ks0 + (buf) * 65536u + (kk) * 16384u;     \
        const unsigned o1_ = adrA_ks1 + (buf) * 65536u + (kk) * 16384u;     \
        DSR(af[dst][0], o0_, ((mih)*2 + 0) * 2048);                         \
        DSR(af[dst][1], o1_, ((mih)*2 + 0) * 2048);                         \
        DSR(af[dst][2], o0_, ((mih)*2 + 1) * 2048);                         \
        DSR(af[dst][3], o1_, ((mih)*2 + 1) * 2048);                         \
    } while (0)

// B frags: nf in {0,1}, both ks. 4 reads.
#define RD_B4(dst, buf, kk) do {                                            \
        const unsigned o0_ = adrB_ks0 + (buf) * 65536u + (2+(kk)) * 16384u; \
        const unsigned o1_ = adrB_ks1 + (buf) * 65536u + (2+(kk)) * 16384u; \
        DSR(bfr[dst][0], o0_, 0);                                           \
        DSR(bfr[dst][1], o1_, 0);                                           \
        DSR(bfr[dst][2], o0_, 2048);                                        \
        DSR(bfr[dst][3], o1_, 2048);                                        \
    } while (0)

#define MM(ca, cb, mih) do {                                                \
        __builtin_amdgcn_s_setprio(1);                                      \
        _Pragma("unroll")                                                   \
        for (int ml_ = 0; ml_ < 2; ++ml_) {                                 \
            _Pragma("unroll")                                               \
            for (int nf_ = 0; nf_ < 2; ++nf_) {                             \
                acc[(mih)*2 + ml_][nf_] =                                   \
                    __builtin_amdgcn_mfma_f32_32x32x16_bf16(                \
                        af[ca][ml_*2 + 0], bfr[cb][nf_*2 + 0],              \
                        acc[(mih)*2 + ml_][nf_], 0, 0, 0);                  \
                acc[(mih)*2 + ml_][nf_] =                                   \
                    __builtin_amdgcn_mfma_f32_32x32x16_bf16(                \
                        af[ca][ml_*2 + 1], bfr[cb][nf_*2 + 1],              \
                        acc[(mih)*2 + ml_][nf_], 0, 0, 0);                  \
            }                                                               \
        }                                                                   \
        __builtin_amdgcn_s_setprio(0);                                      \
    } while (0)

#define BAR  do { __builtin_amdgcn_s_barrier();                             \
                  asm volatile("" ::: "memory"); } while (0)
#define WAIT4 asm volatile("s_waitcnt vmcnt(4)" ::: "memory")
#define WAIT8 asm volatile("s_waitcnt vmcnt(8)" ::: "memory")
#define WAITL(n) do { asm volatile("s_waitcnt lgkmcnt(" #n ")");            \
                      __builtin_amdgcn_sched_barrier(0); } while (0)
#define KADV(k) do { if ((k) < 1504) (k) += 32; } while (0)

    // ---- prologue (R9): tile0 all slots + tile1 k0; preload P1 frags ----
    STG(0, 0, pA0, pA1, 0);
    STG(0, 2, pB0, pB1, 0);
    STG(0, 1, pA0, pA1, 32);
    STG(0, 3, pB0, pB1, 32);
    STG(1, 0, pA0, pA1, 64);
    STG(1, 2, pB0, pB1, 64);
    WAIT8;
    BAR;
    RD_A4(0, 0, 0, 0);
    RD_B4(0, 0, 0);

    int kA = 96, kB = 96;

    // R9 TILE2 schedule verbatim (slots, stages, waits unchanged).
#define TILE2() do {                                                          \
  /*P1*/ STG(1,1,pA0,pA1,kA); KADV(kA); RD_A4(1, 0,0,1);                      \
         WAITL(4); MM(0,0,0);                 BAR;                            \
  /*P2*/ STG(1,3,pB0,pB1,kB); KADV(kB); RD_A4(0, 0,1,0); RD_B4(1, 0,1);      \
         WAITL(8); MM(1,0,1);          WAIT4; BAR;                            \
  /*P3*/ STG(0,0,pA0,pA1,kA); KADV(kA); RD_A4(1, 0,1,1);                      \
         WAITL(4); MM(0,1,0);                 BAR;                            \
  /*P4*/ STG(0,2,pB0,pB1,kB); KADV(kB); RD_A4(0, 1,0,0); RD_B4(0, 1,0);      \
         WAITL(8); MM(1,1,1);          WAIT4; BAR;                            \
  /*P5*/ STG(0,1,pA0,pA1,kA); KADV(kA); RD_A4(1, 1,0,1);                      \
         WAITL(4); MM(0,0,0);                 BAR;                            \
  /*P6*/ STG(0,3,pB0,pB1,kB); KADV(kB); RD_A4(0, 1,1,0); RD_B4(1, 1,1);      \
         WAITL(8); MM(1,0,1);          WAIT4; BAR;                            \
  /*P7*/ STG(1,0,pA0,pA1,kA); KADV(kA); RD_A4(1, 1,1,1);                      \
         WAITL(4); MM(0,1,0);                 BAR;                            \
  /*P8*/ STG(1,2,pB0,pB1,kB); KADV(kB); RD_A4(0, 0,0,0); RD_B4(0, 0,0);      \
         WAITL(8); MM(1,1,1);          WAIT4; BAR;                            \
} while (0)

    #pragma unroll 1
    for (int i = 0; i < 12; ++i) {   // 24 K-tiles(64), 2 per TILE2
        TILE2();
    }

    asm volatile("s_waitcnt lgkmcnt(0)");

    // ---- epilogue: 32x32 C/D layout (m74/m101): col=l31,
    //      row = (reg&3) + 8*(reg>>2) + 4*lhi ----
    const float* __restrict__ bptr = bias + (size_t)org * DIM_OUT;
    #pragma unroll
    for (int nf = 0; nf < 2; ++nf) {
        const int gc = col0 + wc * 64 + nf * 32 + l31;
        const float bv = bptr[gc];
        #pragma unroll
        for (int mf = 0; mf < 4; ++mf) {
            const int grb = row0 + wr * 128 + mf * 32 + 4 * lhi;
            #pragma unroll
            for (int reg = 0; reg < 16; ++reg) {
                const int gr = grb + (reg & 3) + 8 * (reg >> 2);
                out[(size_t)gr * DIM_OUT + gc] = acc[mf][nf][reg] + bv;
            }
        }
    }
#undef STG
#undef DSR
#undef RD_A4
#undef RD_B4
#undef MM
#undef BAR
#undef WAIT4
#undef WAIT8
#undef WAITL
#undef KADV
#undef TILE2
}

// ---------- fallback (R2 kernel) if ws too small ----------
#define BM 128
#define BN 128
#define BK 32
#define LDK 40
union BF8 { unsigned short u[8]; short8 v; };

__global__ __launch_bounds__(256) void mol_gemm_fb(
    const float* __restrict__ x, const int* __restrict__ orgidx,
    const float* __restrict__ weight, const float* __restrict__ bias,
    float* __restrict__ out)
{
    __shared__ __align__(16) unsigned short Alds[2][BM][LDK];
    __shared__ __align__(16) unsigned short Blds[2][BN][LDK];

    const int tid  = threadIdx.x;
    const int lane = tid & 63;
    const int wave = tid >> 6;
    const int wr = wave >> 1, wc = wave & 1;

    const int bid = blockIdx.x;
    const int id  = (bid & 7) * 768 + (bid >> 3);
    const int row0 = (id / 24) * BM;
    const int col0 = (id % 24) * BN;

    const int batch = row0 / DIM_S;
    const int org   = orgidx[batch];
    const float* __restrict__ W = weight + (size_t)org * DIM_IN * DIM_OUT;

    f32x4 acc[4][4] = {};
    const int ar  = tid >> 2;
    const int ak8 = (tid & 3) * 8;
    const int bn  = tid & 127;
    const int bg0 = tid >> 7;
    const float* __restrict__ xbase = x + (size_t)row0 * DIM_IN;
    const float* __restrict__ wbase = W + col0 + bn;

    auto stage = [&](int buf, int k0) {
        #pragma unroll
        for (int i = 0; i < 2; ++i) {
            const int r = ar + 64 * i;
            const float* xp = xbase + (size_t)r * DIM_IN + k0 + ak8;
            const float4 v0 = *reinterpret_cast<const float4*>(xp);
            const float4 v1 = *reinterpret_cast<const float4*>(xp + 4);
            BF8 p;
            p.u[0] = f2bf(v0.x); p.u[1] = f2bf(v0.y);
            p.u[2] = f2bf(v0.z); p.u[3] = f2bf(v0.w);
            p.u[4] = f2bf(v1.x); p.u[5] = f2bf(v1.y);
            p.u[6] = f2bf(v1.z); p.u[7] = f2bf(v1.w);
            *reinterpret_cast<short8*>(&Alds[buf][r][ak8]) = p.v;
        }
        #pragma unroll
        for (int j = 0; j < 2; ++j) {
            const int g = bg0 + 2 * j;
            const float* wp = wbase + (size_t)(k0 + 8 * g) * DIM_OUT;
            BF8 p;
            #pragma unroll
            for (int r = 0; r < 8; ++r) p.u[r] = f2bf(wp[(size_t)r * DIM_OUT]);
            *reinterpret_cast<short8*>(&Blds[buf][bn][8 * g]) = p.v;
        }
    };

    stage(0, 0);
    const int nk = DIM_IN / BK;
    const int kq = (lane >> 4) * 8;
    const int lr = lane & 15;

    for (int t = 0; t < nk; ++t) {
        __syncthreads();
        const int cur = t & 1;
        if (t + 1 < nk) stage(cur ^ 1, (t + 1) * BK);
        short8 a[4], b[4];
        #pragma unroll
        for (int mi = 0; mi < 4; ++mi)
            a[mi] = *reinterpret_cast<const short8*>(&Alds[cur][wr * 64 + mi * 16 + lr][kq]);
        #pragma unroll
        for (int ni = 0; ni < 4; ++ni)
            b[ni] = *reinterpret_cast<const short8*>(&Blds[cur][wc * 64 + ni * 16 + lr][kq]);
        #pragma unroll
        for (int mi = 0; mi < 4; ++mi)
            #pragma unroll
            for (int ni = 0; ni < 4; ++ni)
                acc[mi][ni] = __builtin_amdgcn_mfma_f32_16x16x32_bf16(
                    a[mi], b[ni], acc[mi][ni], 0, 0, 0);
    }

    const float* __restrict__ bptr = bias + (size_t)org * DIM_OUT;
    const int crow = (lane >> 4) * 4;
    const int ccol = lane & 15;
    #pragma unroll
    for (int ni = 0; ni < 4; ++ni) {
        const int gc = col0 + wc * 64 + ni * 16 + ccol;
        const float bv = bptr[gc];
        #pragma unroll
        for (int mi = 0; mi < 4; ++mi) {
            const int gr = row0 + wr * 64 + mi * 16 + crow;
            #pragma unroll
            for (int r = 0; r < 4; ++r)
                out[(size_t)(gr + r) * DIM_OUT + gc] = acc[mi][ni][r] + bv;
        }
    }
}

extern "C" void kernel_launch(void* const* d_in, const int* in_sizes, int n_in,
                              void* d_out, int out_size, void* d_ws, size_t ws_size,
                              hipStream_t stream)
{
    const float* x      = (const float*)d_in[0];
    const int*   orgidx = (const int*)d_in[1];
    const float* weight = (const float*)d_in[2];
    const float* bias   = (const float*)d_in[3];
    float* out = (float*)d_out;

    if (ws_size >= WS_NEED) {
        unsigned short* xbp = (unsigned short*)d_ws;
        unsigned short* wtp = xbp + XB_ELEMS;
        cvt_all<<<dim3(NWT_BLOCKS + NX_BLOCKS), dim3(256), 0, stream>>>(
            x, weight, xbp, wtp);
        mol_gemm_8p<<<dim3(1536), dim3(512), 0, stream>>>(xbp, orgidx, wtp, bias, out);
    } else {
        mol_gemm_fb<<<dim3(6144), dim3(256), 0, stream>>>(x, orgidx, weight, bias, out);
    }
}

// Round 15
// 400.040 us; speedup vs baseline: 1.1486x; 1.0049x over previous
//
#include <hip/hip_runtime.h>
#include <hip/hip_bf16.h>
#include <stdint.h>

typedef __attribute__((ext_vector_type(4)))  float f32x4;
typedef __attribute__((ext_vector_type(16))) float f32x16;
typedef __attribute__((ext_vector_type(8)))  short short8;

#define DIM_S 4096
#define DIM_IN 1536
#define DIM_OUT 3072
#define NB 8
#define NORG 4

#define XB_ELEMS (NB * DIM_S * DIM_IN)      /* 50331648 */
#define WT_ELEMS (NORG * DIM_OUT * DIM_IN)  /* 18874368 */
#define WS_NEED ((size_t)(XB_ELEMS + WT_ELEMS) * 2)
#define NWT_BLOCKS (NORG * 24 * 48)         /* 4608 */
#define NX_BLOCKS 2048

__device__ __forceinline__ unsigned short f2bf(float f) {
    union { __hip_bfloat16 h; unsigned short u; } c;
    c.h = __float2bfloat16(f);
    return c.u;
}

__device__ __forceinline__ void gload16(const void* g, void* l) {
    __builtin_amdgcn_global_load_lds(
        (const __attribute__((address_space(1))) unsigned int*)g,
        (__attribute__((address_space(3))) unsigned int*)l, 16, 0, 0);
}

// ---------- pass 1 (fused): W^T transpose-convert + x convert ----------
__global__ __launch_bounds__(256) void cvt_all(const float* __restrict__ x,
                                               const float* __restrict__ w,
                                               unsigned short* __restrict__ xb,
                                               unsigned short* __restrict__ wt) {
    const int t = threadIdx.x;
    if (blockIdx.x < NWT_BLOCKS) {
        __shared__ unsigned short T[64][68];
        const int bid = blockIdx.x;
        const int org = bid / (24 * 48);
        const int rem = bid % (24 * 48);
        const int k0 = (rem / 48) * 64;
        const int n0 = (rem % 48) * 64;
        const float* __restrict__ wp = w + (size_t)org * DIM_IN * DIM_OUT;
        unsigned short* __restrict__ op = wt + (size_t)org * DIM_OUT * DIM_IN;
        #pragma unroll
        for (int i = 0; i < 4; ++i) {
            const int c = t + 256 * i;
            const int kk = c >> 4, nq = (c & 15) * 4;
            const float4 v = *reinterpret_cast<const float4*>(
                wp + (size_t)(k0 + kk) * DIM_OUT + n0 + nq);
            ushort4 pv;
            pv.x = f2bf(v.x); pv.y = f2bf(v.y); pv.z = f2bf(v.z); pv.w = f2bf(v.w);
            *reinterpret_cast<ushort4*>(&T[kk][nq]) = pv;
        }
        __syncthreads();
        #pragma unroll
        for (int i = 0; i < 2; ++i) {
            const int c = t + 256 * i;
            const int n = c >> 3, k8 = (c & 7) * 8;
            union { unsigned short u[8]; short8 v; } p;
            #pragma unroll
            for (int j = 0; j < 8; ++j) p.u[j] = T[k8 + j][n];
            *reinterpret_cast<short8*>(op + (size_t)(n0 + n) * DIM_IN + k0 + k8) = p.v;
        }
    } else {
        const int nchunk = XB_ELEMS / 8;
        const int xb0 = blockIdx.x - NWT_BLOCKS;
        for (int c = xb0 * 256 + t; c < nchunk; c += NX_BLOCKS * 256) {
            const float4 v0 = *reinterpret_cast<const float4*>(x + (size_t)c * 8);
            const float4 v1 = *reinterpret_cast<const float4*>(x + (size_t)c * 8 + 4);
            union { unsigned short u[8]; short8 v; } p;
            p.u[0] = f2bf(v0.x); p.u[1] = f2bf(v0.y); p.u[2] = f2bf(v0.z); p.u[3] = f2bf(v0.w);
            p.u[4] = f2bf(v1.x); p.u[5] = f2bf(v1.y); p.u[6] = f2bf(v1.z); p.u[7] = f2bf(v1.w);
            *reinterpret_cast<short8*>(xb + (size_t)c * 8) = p.v;
        }
    }
}

// ---------- pass 2: 256x256 8-phase GEMM, 32x32x16 MFMA, 2-bit swizzle ----------
// R14 kernel (passed, 44.5% util) with ONLY the swizzle extended:
//   s(r) = (((r>>3)&1)<<1) | ((r>>4)&1)   (was bit1-only)
// Rationale: 32-row b128 reads kept chunk-bit0 (=lhi) constant per 32-lane
// half -> only even OR odd 16B chunks touched -> half the bank-quads idle
// (2.87e7 conflicts). Row-bit4 in s() makes rows 0-15 take even chunks and
// 16-31 odd -> all 8 quads balanced, matching the measured-zero R7 pattern.
// Staging stays coalesced (per-row 4-chunk permutation; bits 3-4 of slot row
// derive only from rA/l31 for both A and B, both +-128-row offsets).
__global__ __launch_bounds__(512, 2) void mol_gemm_8p(
    const unsigned short* __restrict__ xb, const int* __restrict__ orgidx,
    const unsigned short* __restrict__ wt, const float* __restrict__ bias,
    float* __restrict__ out)
{
    __shared__ __align__(16) unsigned short LDS[2][4][8192];  // 128 KiB

    const int tid  = threadIdx.x;
    const int lane = tid & 63;
    const int wave = tid >> 6;
    const int wr = wave >> 2;      // 0..1  (M half, 128 rows)
    const int wc = wave & 3;       // 0..3  (N quarter, 64 cols)
    const int l31 = lane & 31;
    const int lhi = lane >> 5;     // 0..1

    // XCD-aware remap (R9): 1536 blocks = 8 XCDs x 192; col-fastest.
    const int bid = blockIdx.x;
    const int id  = (bid & 7) * 192 + (bid >> 3);
    const int row0 = (id / 12) * 256;
    const int col0 = (id % 12) * 256;
    const int org  = orgidx[row0 >> 12];

    const unsigned short* __restrict__ Abase = xb + (size_t)row0 * DIM_IN;
    const unsigned short* __restrict__ Bbase =
        wt + (size_t)org * DIM_OUT * DIM_IN + (size_t)col0 * DIM_IN;

    // staging source: row rA = tid>>2, phys chunk tid&3 -> logical chunk
    // (tid&3) ^ s(rA); s bits from rA bits 3,4 = tid bits 5,6.
    const int rA = tid >> 2;
    const int sstg = ((((tid >> 5) & 1) << 1) | ((tid >> 6) & 1));
    const int qs = ((tid & 3) ^ sstg) * 8;
    const unsigned short* pA0 = Abase + (size_t)rA * DIM_IN + qs;
    const unsigned short* pA1 = Abase + (size_t)(128 + rA) * DIM_IN + qs;
    const unsigned short* pB0 = Bbase + (size_t)rA * DIM_IN + qs;
    const unsigned short* pB1 = Bbase + (size_t)(128 + rA) * DIM_IN + qs;

    const int d0 = wave * 512;
    const int d1 = 4096 + wave * 512;

    // read addressing: lane covers row base+l31, k-octet lhi of k-half ks.
    // logical chunk q = 2*ks + lhi; physical p = q ^ s(l31).
    const int swr = ((((l31 >> 3) & 1) << 1) | ((l31 >> 4) & 1));
    const int cks0 = (lhi ^ (swr & 1)) + 2 * ((swr >> 1) & 1);  // p for ks=0
    const unsigned ldsbase = (unsigned)(unsigned long long)
        (const __attribute__((address_space(3))) unsigned short*)&LDS[0][0][0];
    const unsigned rbA = ldsbase + (unsigned)((wr * 128 + l31) * 64);
    const unsigned rbB = ldsbase + (unsigned)((wc * 64  + l31) * 64);
    const unsigned adrA_ks0 = rbA + (unsigned)(cks0 * 16);
    const unsigned adrA_ks1 = rbA + (unsigned)((cks0 ^ 2) * 16);
    const unsigned adrB_ks0 = rbB + (unsigned)(cks0 * 16);
    const unsigned adrB_ks1 = rbB + (unsigned)((cks0 ^ 2) * 16);

    f32x16 acc[4][2] = {};          // [mf][nf]
    short8 af[2][4], bfr[2][4];     // [set][ml*2+ks] / [set][nf*2+ks]

#define STG(buf, slot, p0, p1, kofs) do {                      \
        gload16((p0) + (kofs), &LDS[buf][slot][d0]);           \
        gload16((p1) + (kofs), &LDS[buf][slot][d1]);           \
    } while (0)

#define DSR(dst, addr, imm)                                                 \
    asm volatile("ds_read_b128 %0, %1 offset:%c2"                           \
                 : "=v"(dst) : "v"(addr), "i"(imm))

// A frags for half mih: mf = mih*2 + ml, both ks. 4 reads.
#define RD_A4(dst, buf, kk, mih) do {                                       \
        const unsigned o0_ = adrA_ks0 + (buf) * 65536u + (kk) * 16384u;     \
        const unsigned o1_ = adrA_ks1 + (buf) * 65536u + (kk) * 16384u;     \
        DSR(af[dst][0], o0_, ((mih)*2 + 0) * 2048);                         \
        DSR(af[dst][1], o1_, ((mih)*2 + 0) * 2048);                         \
        DSR(af[dst][2], o0_, ((mih)*2 + 1) * 2048);                         \
        DSR(af[dst][3], o1_, ((mih)*2 + 1) * 2048);                         \
    } while (0)

// B frags: nf in {0,1}, both ks. 4 reads.
#define RD_B4(dst, buf, kk) do {                                            \
        const unsigned o0_ = adrB_ks0 + (buf) * 65536u + (2+(kk)) * 16384u; \
        const unsigned o1_ = adrB_ks1 + (buf) * 65536u + (2+(kk)) * 16384u; \
        DSR(bfr[dst][0], o0_, 0);                                           \
        DSR(bfr[dst][1], o1_, 0);                                           \
        DSR(bfr[dst][2], o0_, 2048);                                        \
        DSR(bfr[dst][3], o1_, 2048);                                        \
    } while (0)

#define MM(ca, cb, mih) do {                                                \
        __builtin_amdgcn_s_setprio(1);                                      \
        _Pragma("unroll")                                                   \
        for (int ml_ = 0; ml_ < 2; ++ml_) {                                 \
            _Pragma("unroll")                                               \
            for (int nf_ = 0; nf_ < 2; ++nf_) {                             \
                acc[(mih)*2 + ml_][nf_] =                                   \
                    __builtin_amdgcn_mfma_f32_32x32x16_bf16(                \
                        af[ca][ml_*2 + 0], bfr[cb][nf_*2 + 0],              \
                        acc[(mih)*2 + ml_][nf_], 0, 0, 0);                  \
                acc[(mih)*2 + ml_][nf_] =                                   \
                    __builtin_amdgcn_mfma_f32_32x32x16_bf16(                \
                        af[ca][ml_*2 + 1], bfr[cb][nf_*2 + 1],              \
                        acc[(mih)*2 + ml_][nf_], 0, 0, 0);                  \
            }                                                               \
        }                                                                   \
        __builtin_amdgcn_s_setprio(0);                                      \
    } while (0)

#define BAR  do { __builtin_amdgcn_s_barrier();                             \
                  asm volatile("" ::: "memory"); } while (0)
#define WAIT4 asm volatile("s_waitcnt vmcnt(4)" ::: "memory")
#define WAIT8 asm volatile("s_waitcnt vmcnt(8)" ::: "memory")
#define WAITL(n) do { asm volatile("s_waitcnt lgkmcnt(" #n ")");            \
                      __builtin_amdgcn_sched_barrier(0); } while (0)
#define KADV(k) do { if ((k) < 1504) (k) += 32; } while (0)

    // ---- prologue (R9): tile0 all slots + tile1 k0; preload P1 frags ----
    STG(0, 0, pA0, pA1, 0);
    STG(0, 2, pB0, pB1, 0);
    STG(0, 1, pA0, pA1, 32);
    STG(0, 3, pB0, pB1, 32);
    STG(1, 0, pA0, pA1, 64);
    STG(1, 2, pB0, pB1, 64);
    WAIT8;
    BAR;
    RD_A4(0, 0, 0, 0);
    RD_B4(0, 0, 0);

    int kA = 96, kB = 96;

    // R9 TILE2 schedule verbatim (slots, stages, waits unchanged).
#define TILE2() do {                                                          \
  /*P1*/ STG(1,1,pA0,pA1,kA); KADV(kA); RD_A4(1, 0,0,1);                      \
         WAITL(4); MM(0,0,0);                 BAR;                            \
  /*P2*/ STG(1,3,pB0,pB1,kB); KADV(kB); RD_A4(0, 0,1,0); RD_B4(1, 0,1);      \
         WAITL(8); MM(1,0,1);          WAIT4; BAR;                            \
  /*P3*/ STG(0,0,pA0,pA1,kA); KADV(kA); RD_A4(1, 0,1,1);                      \
         WAITL(4); MM(0,1,0);                 BAR;                            \
  /*P4*/ STG(0,2,pB0,pB1,kB); KADV(kB); RD_A4(0, 1,0,0); RD_B4(0, 1,0);      \
         WAITL(8); MM(1,1,1);          WAIT4; BAR;                            \
  /*P5*/ STG(0,1,pA0,pA1,kA); KADV(kA); RD_A4(1, 1,0,1);                      \
         WAITL(4); MM(0,0,0);                 BAR;                            \
  /*P6*/ STG(0,3,pB0,pB1,kB); KADV(kB); RD_A4(0, 1,1,0); RD_B4(1, 1,1);      \
         WAITL(8); MM(1,0,1);          WAIT4; BAR;                            \
  /*P7*/ STG(1,0,pA0,pA1,kA); KADV(kA); RD_A4(1, 1,1,1);                      \
         WAITL(4); MM(0,1,0);                 BAR;                            \
  /*P8*/ STG(1,2,pB0,pB1,kB); KADV(kB); RD_A4(0, 0,0,0); RD_B4(0, 0,0);      \
         WAITL(8); MM(1,1,1);          WAIT4; BAR;                            \
} while (0)

    #pragma unroll 1
    for (int i = 0; i < 12; ++i) {   // 24 K-tiles(64), 2 per TILE2
        TILE2();
    }

    asm volatile("s_waitcnt lgkmcnt(0)");

    // ---- epilogue: 32x32 C/D layout (m74/m101): col=l31,
    //      row = (reg&3) + 8*(reg>>2) + 4*lhi ----
    const float* __restrict__ bptr = bias + (size_t)org * DIM_OUT;
    #pragma unroll
    for (int nf = 0; nf < 2; ++nf) {
        const int gc = col0 + wc * 64 + nf * 32 + l31;
        const float bv = bptr[gc];
        #pragma unroll
        for (int mf = 0; mf < 4; ++mf) {
            const int grb = row0 + wr * 128 + mf * 32 + 4 * lhi;
            #pragma unroll
            for (int reg = 0; reg < 16; ++reg) {
                const int gr = grb + (reg & 3) + 8 * (reg >> 2);
                out[(size_t)gr * DIM_OUT + gc] = acc[mf][nf][reg] + bv;
            }
        }
    }
#undef STG
#undef DSR
#undef RD_A4
#undef RD_B4
#undef MM
#undef BAR
#undef WAIT4
#undef WAIT8
#undef WAITL
#undef KADV
#undef TILE2
}

// ---------- fallback (R2 kernel) if ws too small ----------
#define BM 128
#define BN 128
#define BK 32
#define LDK 40
union BF8 { unsigned short u[8]; short8 v; };

__global__ __launch_bounds__(256) void mol_gemm_fb(
    const float* __restrict__ x, const int* __restrict__ orgidx,
    const float* __restrict__ weight, const float* __restrict__ bias,
    float* __restrict__ out)
{
    __shared__ __align__(16) unsigned short Alds[2][BM][LDK];
    __shared__ __align__(16) unsigned short Blds[2][BN][LDK];

    const int tid  = threadIdx.x;
    const int lane = tid & 63;
    const int wave = tid >> 6;
    const int wr = wave >> 1, wc = wave & 1;

    const int bid = blockIdx.x;
    const int id  = (bid & 7) * 768 + (bid >> 3);
    const int row0 = (id / 24) * BM;
    const int col0 = (id % 24) * BN;

    const int batch = row0 / DIM_S;
    const int org   = orgidx[batch];
    const float* __restrict__ W = weight + (size_t)org * DIM_IN * DIM_OUT;

    f32x4 acc[4][4] = {};
    const int ar  = tid >> 2;
    const int ak8 = (tid & 3) * 8;
    const int bn  = tid & 127;
    const int bg0 = tid >> 7;
    const float* __restrict__ xbase = x + (size_t)row0 * DIM_IN;
    const float* __restrict__ wbase = W + col0 + bn;

    auto stage = [&](int buf, int k0) {
        #pragma unroll
        for (int i = 0; i < 2; ++i) {
            const int r = ar + 64 * i;
            const float* xp = xbase + (size_t)r * DIM_IN + k0 + ak8;
            const float4 v0 = *reinterpret_cast<const float4*>(xp);
            const float4 v1 = *reinterpret_cast<const float4*>(xp + 4);
            BF8 p;
            p.u[0] = f2bf(v0.x); p.u[1] = f2bf(v0.y);
            p.u[2] = f2bf(v0.z); p.u[3] = f2bf(v0.w);
            p.u[4] = f2bf(v1.x); p.u[5] = f2bf(v1.y);
            p.u[6] = f2bf(v1.z); p.u[7] = f2bf(v1.w);
            *reinterpret_cast<short8*>(&Alds[buf][r][ak8]) = p.v;
        }
        #pragma unroll
        for (int j = 0; j < 2; ++j) {
            const int g = bg0 + 2 * j;
            const float* wp = wbase + (size_t)(k0 + 8 * g) * DIM_OUT;
            BF8 p;
            #pragma unroll
            for (int r = 0; r < 8; ++r) p.u[r] = f2bf(wp[(size_t)r * DIM_OUT]);
            *reinterpret_cast<short8*>(&Blds[buf][bn][8 * g]) = p.v;
        }
    };

    stage(0, 0);
    const int nk = DIM_IN / BK;
    const int kq = (lane >> 4) * 8;
    const int lr = lane & 15;

    for (int t = 0; t < nk; ++t) {
        __syncthreads();
        const int cur = t & 1;
        if (t + 1 < nk) stage(cur ^ 1, (t + 1) * BK);
        short8 a[4], b[4];
        #pragma unroll
        for (int mi = 0; mi < 4; ++mi)
            a[mi] = *reinterpret_cast<const short8*>(&Alds[cur][wr * 64 + mi * 16 + lr][kq]);
        #pragma unroll
        for (int ni = 0; ni < 4; ++ni)
            b[ni] = *reinterpret_cast<const short8*>(&Blds[cur][wc * 64 + ni * 16 + lr][kq]);
        #pragma unroll
        for (int mi = 0; mi < 4; ++mi)
            #pragma unroll
            for (int ni = 0; ni < 4; ++ni)
                acc[mi][ni] = __builtin_amdgcn_mfma_f32_16x16x32_bf16(
                    a[mi], b[ni], acc[mi][ni], 0, 0, 0);
    }

    const float* __restrict__ bptr = bias + (size_t)org * DIM_OUT;
    const int crow = (lane >> 4) * 4;
    const int ccol = lane & 15;
    #pragma unroll
    for (int ni = 0; ni < 4; ++ni) {
        const int gc = col0 + wc * 64 + ni * 16 + ccol;
        const float bv = bptr[gc];
        #pragma unroll
        for (int mi = 0; mi < 4; ++mi) {
            const int gr = row0 + wr * 64 + mi * 16 + crow;
            #pragma unroll
            for (int r = 0; r < 4; ++r)
                out[(size_t)(gr + r) * DIM_OUT + gc] = acc[mi][ni][r] + bv;
        }
    }
}

extern "C" void kernel_launch(void* const* d_in, const int* in_sizes, int n_in,
                              void* d_out, int out_size, void* d_ws, size_t ws_size,
                              hipStream_t stream)
{
    const float* x      = (const float*)d_in[0];
    const int*   orgidx = (const int*)d_in[1];
    const float* weight = (const float*)d_in[2];
    const float* bias   = (const float*)d_in[3];
    float* out = (float*)d_out;

    if (ws_size >= WS_NEED) {
        unsigned short* xbp = (unsigned short*)d_ws;
        unsigned short* wtp = xbp + XB_ELEMS;
        cvt_all<<<dim3(NWT_BLOCKS + NX_BLOCKS), dim3(256), 0, stream>>>(
            x, weight, xbp, wtp);
        mol_gemm_8p<<<dim3(1536), dim3(512), 0, stream>>>(xbp, orgidx, wtp, bias, out);
    } else {
        mol_gemm_fb<<<dim3(6144), dim3(256), 0, stream>>>(x, orgidx, weight, bias, out);
    }
}